// Round 1
// baseline (42995.871 us; speedup 1.0000x reference)
//
#include <hip/hip_runtime.h>
#include <math.h>

#define N_IMG 1024
#define C_IN 512
#define C_MID 1024
#define HW 7
#define SP 49
#define NCOLS (N_IMG*SP)      /* 50176 */
#define K1 (C_IN*9)           /* 4608 */
#define K2 (C_MID*9 + C_IN)   /* 9728: conv2 + fused 1x1 shortcut */
#define BM 128
#define BN 128
#define BK 16

// ---------------------------------------------------------------------------
// Conv as implicit GEMM: C[oc, col] = sum_k A[oc,k] * im2col[k, col]
// MODE 0: A = w1 (K=4608), B from X, out = h = relu(conv1)
// MODE 1: A = [w2 | wd] (K=9728), B from [im2col(h) | X], out = embedded = relu(.)
// Grid (392, 8), 256 threads, 128x128 tile, 8x8 micro-tile.
// ---------------------------------------------------------------------------
template<int MODE>
__global__ __launch_bounds__(256)
void conv_gemm(const float* __restrict__ X, const float* __restrict__ H,
               const float* __restrict__ W, const float* __restrict__ WD,
               float* __restrict__ out)
{
    constexpr int K = MODE ? K2 : K1;
    __shared__ float As[BK][BM+4];
    __shared__ float Bs[BK][BN+4];

    const int tid = threadIdx.x;
    const int bn = blockIdx.x;
    const int bm = blockIdx.y;
    const int tx = tid & 15;
    const int ty = tid >> 4;

    // A-load: thread -> (row, 8 consecutive k)
    const int arow = tid >> 1;
    const int acol = (tid & 1) * 8;
    const int grow = bm*BM + arow;

    // B-load: thread -> k-row (tid>>4), cols (tid&15) + 16*jj (coalesced lanes)
    const int bk = tid >> 4;
    const int bc = tid & 15;
    int n8[8], iy8[8], ix8[8];
    #pragma unroll
    for (int jj = 0; jj < 8; jj++) {
        int col = bn*BN + bc + 16*jj;
        int n = col / SP;
        int p = col - n*SP;
        int y = p / HW;
        n8[jj] = n; iy8[jj] = y; ix8[jj] = p - y*HW;
    }

    float acc[8][8];
    #pragma unroll
    for (int i = 0; i < 8; i++)
        #pragma unroll
        for (int j = 0; j < 8; j++) acc[i][j] = 0.f;

    for (int k0 = 0; k0 < K; k0 += BK) {
        // ---- stage A tile (transposed into As[k][m]) ----
        {
            int kk = k0 + acol;
            const float* src;
            if (MODE == 0) {
                src = W + grow*K1 + kk;
            } else {
                src = (kk < C_MID*9) ? (W + grow*(C_MID*9) + kk)
                                     : (WD + grow*C_IN + (kk - C_MID*9));
            }
            float4 v0 = *(const float4*)(src);
            float4 v1 = *(const float4*)(src + 4);
            As[acol+0][arow] = v0.x; As[acol+1][arow] = v0.y;
            As[acol+2][arow] = v0.z; As[acol+3][arow] = v0.w;
            As[acol+4][arow] = v1.x; As[acol+5][arow] = v1.y;
            As[acol+6][arow] = v1.z; As[acol+7][arow] = v1.w;
        }
        // ---- stage B tile (im2col gather) ----
        {
            int k = k0 + bk;
            if (MODE == 0 || k < C_MID*9) {
                int c = k / 9;
                int r = k - c*9;
                int ky = r/3 - 1;
                int kx = (r - (r/3)*3) - 1;
                const float* SRC = (MODE == 0) ? X : H;
                const int CS = (MODE == 0) ? C_IN : C_MID;
                #pragma unroll
                for (int jj = 0; jj < 8; jj++) {
                    int iy = iy8[jj] + ky, ix = ix8[jj] + kx;
                    float v = 0.f;
                    if ((unsigned)iy < HW && (unsigned)ix < HW)
                        v = SRC[((n8[jj]*CS + c)*HW + iy)*HW + ix];
                    Bs[bk][bc + 16*jj] = v;
                }
            } else {
                int c = k - C_MID*9;
                #pragma unroll
                for (int jj = 0; jj < 8; jj++) {
                    Bs[bk][bc + 16*jj] =
                        X[((n8[jj]*C_IN + c)*HW + iy8[jj])*HW + ix8[jj]];
                }
            }
        }
        __syncthreads();
        #pragma unroll
        for (int kk = 0; kk < BK; kk++) {
            float a[8], b[8];
            *(float4*)&a[0] = *(const float4*)&As[kk][ty*8];
            *(float4*)&a[4] = *(const float4*)&As[kk][ty*8+4];
            *(float4*)&b[0] = *(const float4*)&Bs[kk][tx*8];
            *(float4*)&b[4] = *(const float4*)&Bs[kk][tx*8+4];
            #pragma unroll
            for (int i = 0; i < 8; i++)
                #pragma unroll
                for (int j = 0; j < 8; j++)
                    acc[i][j] = fmaf(a[i], b[j], acc[i][j]);
        }
        __syncthreads();
    }
    // ---- epilogue: relu + store NCHW ----
    #pragma unroll
    for (int j = 0; j < 8; j++) {
        int col = bn*BN + tx*8 + j;
        int n = col / SP;
        int p = col - n*SP;
        #pragma unroll
        for (int i = 0; i < 8; i++) {
            int m = bm*BM + ty*8 + i;
            out[(n*C_MID + m)*SP + p] = fmaxf(acc[i][j], 0.f);
        }
    }
}

// ---------------------------------------------------------------------------
__global__ __launch_bounds__(256)
void pool_kernel(const float* __restrict__ emb, float* __restrict__ flat)
{
    int n = blockIdx.x;
    for (int c = threadIdx.x; c < C_MID; c += 256) {
        const float* p = emb + (n*C_MID + c)*SP;
        float s = 0.f;
        #pragma unroll
        for (int i = 0; i < SP; i++) s += p[i];
        flat[n*C_MID + c] = s / 49.0f;
    }
}

// ---------------------------------------------------------------------------
// Per-image heads: 45 dot products (9 cls + 36 reg), softmax, box decode+clip.
// ---------------------------------------------------------------------------
__global__ __launch_bounds__(64)
void head_kernel(const float* __restrict__ flat,
                 const float* __restrict__ cls_w, const float* __restrict__ cls_b,
                 const float* __restrict__ reg_w, const float* __restrict__ reg_b,
                 const float* __restrict__ props,
                 float* __restrict__ cls_out, float* __restrict__ reg_out,
                 float* __restrict__ pbox, float* __restrict__ pscore)
{
    int n = blockIdx.x;
    __shared__ float f[C_MID];
    __shared__ float logits[9];
    __shared__ float regs[36];
    for (int c = threadIdx.x; c < C_MID; c += 64) f[c] = flat[n*C_MID + c];
    __syncthreads();
    int o = threadIdx.x;
    if (o < 45) {
        const float* w = (o < 9) ? (cls_w + o*C_MID) : (reg_w + (o-9)*C_MID);
        float a = (o < 9) ? cls_b[o] : reg_b[o-9];
        for (int c = 0; c < C_MID; c++) a = fmaf(f[c], w[c], a);
        if (o < 9) { cls_out[n*9 + o] = a; logits[o] = a; }
        else       { reg_out[n*36 + (o-9)] = a; regs[o-9] = a; }
    }
    __syncthreads();
    if (o < 9) {
        float m = logits[0];
        for (int i = 1; i < 9; i++) m = fmaxf(m, logits[i]);
        float se = 0.f;
        for (int i = 0; i < 9; i++) se += expf(logits[i] - m);
        pscore[n*9 + o] = expf(logits[o] - m) / se;
        {
            #pragma clang fp contract(off)
            float x1 = props[n*4+0], y1 = props[n*4+1];
            float x2 = props[n*4+2], y2 = props[n*4+3];
            float pw = x2 - x1, ph = y2 - y1;
            float pcx = x1 + 0.5f*pw, pcy = y1 + 0.5f*ph;
            float dx = regs[o*4+0] / 10.0f;
            float dy = regs[o*4+1] / 10.0f;
            float dw = fminf(regs[o*4+2] / 5.0f, 4.135166556742356f);
            float dh = fminf(regs[o*4+3] / 5.0f, 4.135166556742356f);
            float ncx = dx*pw + pcx, ncy = dy*ph + pcy;
            float nw = expf(dw)*pw,  nh = expf(dh)*ph;
            float bx1 = ncx - 0.5f*nw, by1 = ncy - 0.5f*nh;
            float bx2 = ncx + 0.5f*nw, by2 = ncy + 0.5f*nh;
            bx1 = fminf(fmaxf(bx1, 0.f), 640.f);
            by1 = fminf(fmaxf(by1, 0.f), 384.f);
            bx2 = fminf(fmaxf(bx2, 0.f), 640.f);
            by2 = fminf(fmaxf(by2, 0.f), 384.f);
            float* dst = pbox + (n*9 + o)*4;
            dst[0] = bx1; dst[1] = by1; dst[2] = bx2; dst[3] = by2;
        }
    }
}

// ---------------------------------------------------------------------------
// Per-image (2 blocks): candidate mask -> bitonic sort of 4096 (score desc,
// idx asc, matching lax.top_k ties) -> top-512 -> IoU bitmask (class-offset
// boxes, exact reference formula) -> serial greedy NMS -> first 100 kept.
// ---------------------------------------------------------------------------
__global__ __launch_bounds__(1024)
void nms_kernel(const float* __restrict__ pbox, const float* __restrict__ pscore,
                float* __restrict__ dbox, float* __restrict__ dsc,
                float* __restrict__ dlab, float* __restrict__ dval)
{
    #pragma clang fp contract(off)
    const int b = blockIdx.x;
    const int tid = threadIdx.x;
    __shared__ unsigned long long mbuf[4096];   // 32 KB: sort arrays, then masks
    __shared__ float s512[512];
    __shared__ int   id512[512];
    __shared__ float obx[512][4];
    __shared__ unsigned long long keepw[8];
    float* sc = (float*)mbuf;
    int*   si = (int*)(sc + 4096);
    const float NEG_INF = -__builtin_inff();

    for (int i = tid; i < 4096; i += 1024) {
        int p = i >> 3;
        int c = (i & 7) + 1;
        int n = b*512 + p;
        float s = pscore[n*9 + c];
        const float* bb = pbox + (n*9 + c)*4;
        float w = bb[2] - bb[0], h = bb[3] - bb[1];
        bool valid = (s > 0.05f) && (w >= 0.01f) && (h >= 0.01f);
        sc[i] = valid ? s : NEG_INF;
        si[i] = i;
    }
    __syncthreads();
    for (int k = 2; k <= 4096; k <<= 1) {
        for (int j = k >> 1; j > 0; j >>= 1) {
            for (int i = tid; i < 4096; i += 1024) {
                int ixj = i ^ j;
                if (ixj > i) {
                    float s1 = sc[i], s2 = sc[ixj];
                    int i1 = si[i], i2 = si[ixj];
                    bool before12 = (s1 > s2) || ((s1 == s2) && (i1 < i2));
                    bool up = ((i & k) == 0);
                    if (up ? !before12 : before12) {
                        sc[i] = s2; sc[ixj] = s1;
                        si[i] = i2; si[ixj] = i1;
                    }
                }
            }
            __syncthreads();
        }
    }
    if (tid < 512) {
        float s = sc[tid];
        int id = si[tid];
        s512[tid] = s;
        id512[tid] = id;
        int c = (id & 7) + 1;
        int n = b*512 + (id >> 3);
        float off = (float)c * 641.0f;   // (max(H,W)+1) * label
        const float* bb = pbox + (n*9 + c)*4;
        obx[tid][0] = bb[0] + off;
        obx[tid][1] = bb[1] + off;
        obx[tid][2] = bb[2] + off;
        obx[tid][3] = bb[3] + off;
    }
    __syncthreads();
    unsigned long long* mask = mbuf;   // [512][8]
    for (int idx = tid; idx < 4096; idx += 1024) {
        int i = idx >> 3, w = idx & 7;
        float ax1 = obx[i][0], ay1 = obx[i][1], ax2 = obx[i][2], ay2 = obx[i][3];
        float aarea = (ax2 - ax1) * (ay2 - ay1);
        unsigned long long m = 0;
        int j0 = w << 6;
        for (int jj = 0; jj < 64; jj++) {
            int j = j0 + jj;
            if (j > i) {
                float bx1 = obx[j][0], by1 = obx[j][1];
                float bx2 = obx[j][2], by2 = obx[j][3];
                float barea = (bx2 - bx1) * (by2 - by1);
                float lx = fmaxf(ax1, bx1), ly = fmaxf(ay1, by1);
                float rx = fminf(ax2, bx2), ry = fminf(ay2, by2);
                float iw = fmaxf(rx - lx, 0.f), ih = fmaxf(ry - ly, 0.f);
                float inter = iw * ih;
                float iou = inter / fmaxf(aarea + barea - inter, 1e-8f);
                if (iou > 0.5f) m |= (1ull << jj);
            }
        }
        mask[(i << 3) + w] = m;
    }
    if (tid < 8) {
        unsigned long long kw = 0;
        for (int jj = 0; jj < 64; jj++)
            if (s512[(tid << 6) + jj] != NEG_INF) kw |= (1ull << jj);
        keepw[tid] = kw;
    }
    __syncthreads();
    if (tid == 0) {
        for (int i = 0; i < 512; i++) {
            if ((keepw[i >> 6] >> (i & 63)) & 1ull) {
                const unsigned long long* mi = mask + (i << 3);
                #pragma unroll
                for (int w = 0; w < 8; w++) keepw[w] &= ~mi[w];
            }
        }
        int cnt = 0;
        for (int i = 0; i < 512 && cnt < 100; i++) {
            if ((keepw[i >> 6] >> (i & 63)) & 1ull) {
                int id = id512[i];
                int c = (id & 7) + 1;
                int n = b*512 + (id >> 3);
                const float* bb = pbox + (n*9 + c)*4;
                float* db = dbox + (b*100 + cnt)*4;
                db[0] = bb[0]; db[1] = bb[1]; db[2] = bb[2]; db[3] = bb[3];
                dsc[b*100 + cnt] = s512[i];
                dlab[b*100 + cnt] = (float)c;
                dval[b*100 + cnt] = 1.0f;
                cnt++;
            }
        }
        for (; cnt < 100; cnt++) {
            float* db = dbox + (b*100 + cnt)*4;
            db[0] = 0.f; db[1] = 0.f; db[2] = 0.f; db[3] = 0.f;
            dsc[b*100 + cnt] = 0.f;
            dlab[b*100 + cnt] = 0.f;
            dval[b*100 + cnt] = 0.f;
        }
    }
}

// ---------------------------------------------------------------------------
extern "C" void kernel_launch(void* const* d_in, const int* in_sizes, int n_in,
                              void* d_out, int out_size, void* d_ws, size_t ws_size,
                              hipStream_t stream)
{
    const float* X      = (const float*)d_in[0];
    const float* props  = (const float*)d_in[1];
    const float* w1     = (const float*)d_in[2];
    const float* w2     = (const float*)d_in[3];
    const float* wd     = (const float*)d_in[4];
    const float* cls_w  = (const float*)d_in[5];
    const float* cls_b  = (const float*)d_in[6];
    const float* reg_w  = (const float*)d_in[7];
    const float* reg_b  = (const float*)d_in[8];

    float* out     = (float*)d_out;
    float* emb     = out;                        // 1024*1024*49 = 51380224
    float* cls_out = out + 51380224;             // 1024*9
    float* reg_out = cls_out + 9216;             // 1024*36
    float* dbox    = reg_out + 36864;            // 2*100*4
    float* dsc     = dbox + 800;                 // 2*100
    float* dlab    = dsc + 200;                  // 2*100
    float* dval    = dlab + 200;                 // 2*100

    float* ws     = (float*)d_ws;
    float* h      = ws;                                      // 51380224 floats
    float* flat   = h + (size_t)N_IMG*C_MID*SP;              // 1048576
    float* pbox   = flat + (size_t)N_IMG*C_MID;              // 36864
    float* pscore = pbox + (size_t)N_IMG*9*4;                // 9216

    dim3 cgrid(NCOLS/BN, C_MID/BM);
    conv_gemm<0><<<cgrid, 256, 0, stream>>>(X, nullptr, w1, nullptr, h);
    conv_gemm<1><<<cgrid, 256, 0, stream>>>(X, h, w2, wd, emb);
    pool_kernel<<<N_IMG, 256, 0, stream>>>(emb, flat);
    head_kernel<<<N_IMG, 64, 0, stream>>>(flat, cls_w, cls_b, reg_w, reg_b, props,
                                          cls_out, reg_out, pbox, pscore);
    nms_kernel<<<2, 1024, 0, stream>>>(pbox, pscore, dbox, dsc, dlab, dval);
}